// Round 2
// baseline (1049.860 us; speedup 1.0000x reference)
//
#include <hip/hip_runtime.h>
#include <math.h>
#include <stdint.h>

#define LVLS 16
#define TSZ (1 << 18)
#define TMASK (TSZ - 1)
#define PI2 2654435761u

struct NsParams { int ns[LVLS]; };

__global__ __launch_bounds__(256, 4) void hash_enc_kernel(
    const float* __restrict__ xy,
    const float* __restrict__ tables,
    float* __restrict__ out,
    int B, NsParams prm)
{
    __shared__ float smem[32 * 257];
    const int tid = threadIdx.x;
    const int i = blockIdx.x * 256 + tid;
    const int iclamp = i < B ? i : (B - 1);

    float2 q = reinterpret_cast<const float2*>(xy)[iclamp];
    float x = fminf(fmaxf(q.x, 0.0f), 1.0f);
    float y = fminf(fmaxf(q.y, 0.0f), 1.0f);

    float acc[2 * LVLS];

    #pragma unroll
    for (int l = 0; l < LVLS; ++l) {
        const int Nl = prm.ns[l];
        const float fN = (float)Nl;
        float px = x * fN, py = y * fN;
        float fx0 = floorf(px), fy0 = floorf(py);
        int x0 = (int)fx0, y0 = (int)fy0;
        int x1 = min(x0 + 1, Nl), y1 = min(y0 + 1, Nl);
        float wx = px - fx0, wy = py - fy0;

        const float2* tb = reinterpret_cast<const float2*>(tables) + (size_t)l * TSZ;

        uint32_t i00, i10, i01, i11;
        if ((long long)(Nl + 1) * (long long)(Nl + 1) <= (long long)TSZ) {
            uint32_t s = (uint32_t)(Nl + 1);
            i00 = (uint32_t)x0 * s + (uint32_t)y0;
            i10 = (uint32_t)x1 * s + (uint32_t)y0;
            i01 = (uint32_t)x0 * s + (uint32_t)y1;
            i11 = (uint32_t)x1 * s + (uint32_t)y1;
        } else {
            uint32_t hy0 = (uint32_t)y0 * PI2;
            uint32_t hy1 = (uint32_t)y1 * PI2;
            i00 = ((uint32_t)x0 ^ hy0) & TMASK;
            i10 = ((uint32_t)x1 ^ hy0) & TMASK;
            i01 = ((uint32_t)x0 ^ hy1) & TMASK;
            i11 = ((uint32_t)x1 ^ hy1) & TMASK;
        }

        float2 f00 = tb[i00];
        float2 f10 = tb[i10];
        float2 f01 = tb[i01];
        float2 f11 = tb[i11];

        float omwx = 1.0f - wx, omwy = 1.0f - wy;
        float f0a = f00.x * omwx + f10.x * wx;
        float f0b = f00.y * omwx + f10.y * wx;
        float f1a = f01.x * omwx + f11.x * wx;
        float f1b = f01.y * omwx + f11.y * wx;
        acc[2 * l]     = f0a * omwy + f1a * wy;
        acc[2 * l + 1] = f0b * omwy + f1b * wy;
    }

    // Stage transposed in LDS, then fully-coalesced float4 stores.
    #pragma unroll
    for (int c = 0; c < 32; ++c)
        smem[c * 257 + tid] = (i < B) ? acc[c] : 0.0f;
    __syncthreads();

    float4* out4 = reinterpret_cast<float4*>(out) + (size_t)blockIdx.x * 2048;
    const size_t out4_total = (size_t)B * 8;  // B*32 floats / 4
    const int a = tid & 7, b = tid >> 3;
    #pragma unroll
    for (int j = 0; j < 8; ++j) {
        size_t gidx = (size_t)blockIdx.x * 2048 + j * 256 + tid;
        if (gidx < out4_total) {
            float4 v;
            v.x = smem[(4 * a + 0) * 257 + 32 * j + b];
            v.y = smem[(4 * a + 1) * 257 + 32 * j + b];
            v.z = smem[(4 * a + 2) * 257 + 32 * j + b];
            v.w = smem[(4 * a + 3) * 257 + 32 * j + b];
            out4[j * 256 + tid] = v;
        }
    }
}

extern "C" void kernel_launch(void* const* d_in, const int* in_sizes, int n_in,
                              void* d_out, int out_size, void* d_ws, size_t ws_size,
                              hipStream_t stream) {
    const float* xy     = (const float*)d_in[0];
    const float* tables = (const float*)d_in[1];
    float* out = (float*)d_out;
    const int B = in_sizes[0] / 2;

    // Replicate Python's NS computation bit-exactly (same libm double ops).
    NsParams prm;
    const double bb = exp((log(131072.0) - log(16.0)) / 15.0);
    for (int l = 0; l < LVLS; ++l)
        prm.ns[l] = (int)floor(16.0 * pow(bb, (double)l));

    const int grid = (B + 255) / 256;
    hipLaunchKernelGGL(hash_enc_kernel, dim3(grid), dim3(256), 0, stream,
                       xy, tables, out, B, prm);
}